// Round 1
// baseline (2278.231 us; speedup 1.0000x reference)
//
#include <hip/hip_runtime.h>

#define N_ROWS 16384
#define D_IN   768
#define D_LAT  12288
#define TOPK   32
#define POOLCAP 96
#define RANKT   44u

typedef float  f32x4  __attribute__((ext_vector_type(4)));
typedef __bf16 bf16x8 __attribute__((ext_vector_type(8)));

__device__ __forceinline__ unsigned short f2bf(float f) {
  unsigned int u = __float_as_uint(f);
  u += 0x7FFFu + ((u >> 16) & 1u);   // round-to-nearest-even
  return (unsigned short)(u >> 16);
}

// ---------------- cast fp32 -> bf16, x4 vectorized ----------------
__global__ __launch_bounds__(256) void cast_kernel(const float* __restrict__ in,
                                                   unsigned short* __restrict__ out, int n4) {
  int i = blockIdx.x * 256 + threadIdx.x;
  if (i < n4) {
    float4 f = ((const float4*)in)[i];
    ushort4 o;
    o.x = f2bf(f.x); o.y = f2bf(f.y); o.z = f2bf(f.z); o.w = f2bf(f.w);
    ((ushort4*)out)[i] = o;
  }
}

// ---------------- transpose W_dec [768][12288] -> W_decT [12288][768] ----------------
__global__ __launch_bounds__(256) void transpose_kernel(const float* __restrict__ W,
                                                        float* __restrict__ WT) {
  __shared__ float tile[32][33];
  int tx = threadIdx.x & 31, ty = threadIdx.x >> 5;   // 32 x 8
  int l = blockIdx.x * 32 + tx;
  #pragma unroll
  for (int r = 0; r < 32; r += 8) {
    int d = blockIdx.y * 32 + ty + r;
    tile[ty + r][tx] = W[(size_t)d * D_LAT + l];
  }
  __syncthreads();
  int d2 = blockIdx.y * 32 + tx;
  #pragma unroll
  for (int r = 0; r < 32; r += 8) {
    int l2 = blockIdx.x * 32 + ty + r;
    WT[(size_t)l2 * D_IN + d2] = tile[tx][ty + r];
  }
}

// ---------------- bf16 MFMA GEMM: scores = relu(x @ W_enc^T) as bf16 ----------------
// A = x_bf16 [16384][768], B = W_enc_bf16 [12288][768] (both K-major). 128x128 tile, BK=32.
__global__ __launch_bounds__(256) void gemm_score_kernel(
    const unsigned short* __restrict__ Abf,
    const unsigned short* __restrict__ Bbf,
    unsigned short* __restrict__ scores) {
  __shared__ unsigned short smem[8192];   // 16 KB: A tile 128x32 | B tile 128x32
  const int bm0 = blockIdx.y * 128;
  const int bn0 = blockIdx.x * 128;
  const int tid  = threadIdx.x;
  const int wave = tid >> 6;
  const int lane = tid & 63;
  const int wr = wave >> 1, wc = wave & 1;
  const int m_in = lane & 15;
  const int q    = lane >> 4;

  f32x4 acc[4][4] = {};

  for (int kt = 0; kt < D_IN; kt += 32) {
    #pragma unroll
    for (int j = 0; j < 4; ++j) {
      int c = (wave * 4 + j) * 64 + lane;      // 16B chunk id, [0,1024)
      const unsigned short* g;
      if (c < 512) {                            // A tile: row = c>>2, kchunk = c&3
        int r = c >> 2, kc = c & 3;
        g = Abf + (size_t)(bm0 + r) * D_IN + kt + kc * 8;
      } else {                                  // B tile
        int c2 = c - 512;
        int r = c2 >> 2, kc = c2 & 3;
        g = Bbf + (size_t)(bn0 + r) * D_IN + kt + kc * 8;
      }
      unsigned short* l = smem + (wave * 4 + j) * 512;   // wave-uniform base, 1KB/instr
      __builtin_amdgcn_global_load_lds(
          (const __attribute__((address_space(1))) unsigned int*)g,
          (__attribute__((address_space(3))) unsigned int*)l,
          16, 0, 0);
    }
    __syncthreads();
    const unsigned short* As = smem;           // [128][32]
    const unsigned short* Bs = smem + 4096;    // [128][32]
    bf16x8 a[4], b[4];
    #pragma unroll
    for (int f = 0; f < 4; ++f) {
      a[f] = *(const bf16x8*)(As + (wr * 64 + f * 16 + m_in) * 32 + q * 8);
      b[f] = *(const bf16x8*)(Bs + (wc * 64 + f * 16 + m_in) * 32 + q * 8);
    }
    #pragma unroll
    for (int fm = 0; fm < 4; ++fm)
      #pragma unroll
      for (int fn = 0; fn < 4; ++fn)
        acc[fm][fn] = __builtin_amdgcn_mfma_f32_16x16x32_bf16(a[fm], b[fn], acc[fm][fn], 0, 0, 0);
    __syncthreads();
  }

  // epilogue: relu -> bf16 scores.  C/D: col = lane&15, row = (lane>>4)*4 + reg
  #pragma unroll
  for (int fm = 0; fm < 4; ++fm) {
    #pragma unroll
    for (int fn = 0; fn < 4; ++fn) {
      int col = bn0 + wc * 64 + fn * 16 + m_in;
      #pragma unroll
      for (int r = 0; r < 4; ++r) {
        int row = bm0 + wr * 64 + fm * 16 + q * 4 + r;
        float v = fmaxf(acc[fm][fn][r], 0.0f);
        scores[(size_t)row * D_LAT + col] = f2bf(v);
      }
    }
  }
}

// ---------------- per-row candidate select + exact fp64 rescore ----------------
__global__ __launch_bounds__(256) void topk_kernel(
    const unsigned short* __restrict__ scores,
    const float* __restrict__ x,
    const float* __restrict__ Wenc,
    int* __restrict__ sel_idx,
    float* __restrict__ sel_val) {
  __shared__ unsigned short srow[D_LAT];
  __shared__ unsigned int hist[256];
  __shared__ float xrow[D_IN];
  __shared__ int poolIdx[POOLCAP];
  __shared__ double cscore[POOLCAP];
  __shared__ int sB1, sBase, sCnt;
  __shared__ unsigned int sT;

  const int row  = blockIdx.x;
  const int tid  = threadIdx.x;
  const int lane = tid & 63;
  const int wave = tid >> 6;

  // load bf16 score row into LDS (16B loads)
  {
    const uint4* src = (const uint4*)(scores + (size_t)row * D_LAT);
    uint4* dst = (uint4*)srow;
    for (int i = tid; i < D_LAT / 8; i += 256) dst[i] = src[i];
  }
  for (int i = tid; i < D_IN; i += 256) xrow[i] = x[(size_t)row * D_IN + i];
  hist[tid & 255] = 0;
  if (tid == 0) sCnt = 0;
  __syncthreads();

  // pass 1: histogram of high byte (scores >= 0 => uint16 order == value order)
  for (int k = 0; k < D_LAT / 256; ++k) {
    unsigned int v = srow[k * 256 + tid];
    atomicAdd(&hist[v >> 8], 1u);
  }
  __syncthreads();
  {
    unsigned int suf = 0;
    for (int j = tid; j < 256; ++j) suf += hist[j];
    unsigned int above = suf - hist[tid];
    if (suf >= RANKT && above < RANKT) { sB1 = tid; sBase = (int)above; }
  }
  __syncthreads();
  const int B1 = sB1, base = sBase;
  hist[tid] = 0;
  __syncthreads();
  // pass 2: refine within bin B1 using low byte
  for (int k = 0; k < D_LAT / 256; ++k) {
    unsigned int v = srow[k * 256 + tid];
    if ((int)(v >> 8) == B1) atomicAdd(&hist[v & 255u], 1u);
  }
  __syncthreads();
  {
    unsigned int suf = (unsigned int)base;
    for (int j = tid; j < 256; ++j) suf += hist[j];
    unsigned int above = suf - hist[tid];
    if (suf >= RANKT && above < RANKT) sT = ((unsigned int)B1 << 8) | (unsigned int)tid;
  }
  __syncthreads();
  const unsigned int T = sT;
  // collect candidate pool (count >= RANKT by construction)
  for (int k = 0; k < D_LAT / 256; ++k) {
    int i = k * 256 + tid;
    unsigned int v = srow[i];
    if (v >= T) {
      int p = atomicAdd(&sCnt, 1);
      if (p < POOLCAP) poolIdx[p] = i;
    }
  }
  __syncthreads();
  const int poolN = sCnt < POOLCAP ? sCnt : POOLCAP;

  // exact fp64 rescore of candidates (deterministic tree reduce)
  for (int c = wave; c < poolN; c += 4) {
    const float* w = Wenc + (size_t)poolIdx[c] * D_IN;
    double p = 0.0;
    #pragma unroll
    for (int i = 0; i < D_IN / 64; ++i) {
      int e = i * 64 + lane;
      p += (double)xrow[e] * (double)w[e];
    }
    #pragma unroll
    for (int off = 32; off >= 1; off >>= 1) p += __shfl_down(p, off);
    if (lane == 0) cscore[c] = p;
  }
  __syncthreads();

  // exact rank; ties broken by lower index (matches top_k)
  if (tid < poolN) {
    double s = cscore[tid];
    int myidx = poolIdx[tid];
    int r = 0;
    for (int j = 0; j < poolN; ++j) {
      double sj = cscore[j];
      r += (sj > s) || (sj == s && poolIdx[j] < myidx);
    }
    if (r < TOPK) {
      double sv = s > 0.0 ? s : 0.0;   // relu (top-32 are positive anyway)
      sel_idx[(size_t)row * TOPK + r] = myidx;
      sel_val[(size_t)row * TOPK + r] = (float)sv;
    }
  }
}

// ---------------- scatter selected values into zeroed z ----------------
__global__ __launch_bounds__(256) void scatter_kernel(const int* __restrict__ sel_idx,
                                                      const float* __restrict__ sel_val,
                                                      float* __restrict__ z) {
  int i = blockIdx.x * 256 + threadIdx.x;
  if (i < N_ROWS * TOPK) {
    int row = i >> 5;
    z[(size_t)row * D_LAT + sel_idx[i]] = sel_val[i];
  }
}

// ---------------- sparse decode: x_hat[row] = sum_j val_j * W_decT[idx_j][:] ----------------
__global__ __launch_bounds__(256) void decode_kernel(const int* __restrict__ sel_idx,
                                                     const float* __restrict__ sel_val,
                                                     const float* __restrict__ WdT,
                                                     float* __restrict__ xhat) {
  __shared__ int   sidx[TOPK];
  __shared__ float sval[TOPK];
  const int row = blockIdx.x;
  const int tid = threadIdx.x;
  if (tid < TOPK) {
    sidx[tid] = sel_idx[(size_t)row * TOPK + tid];
    sval[tid] = sel_val[(size_t)row * TOPK + tid];
  }
  __syncthreads();
  float a0 = 0.f, a1 = 0.f, a2 = 0.f;
  #pragma unroll 8
  for (int j = 0; j < TOPK; ++j) {
    const float* w = WdT + (size_t)sidx[j] * D_IN;
    float v = sval[j];
    a0 += v * w[tid];
    a1 += v * w[tid + 256];
    a2 += v * w[tid + 512];
  }
  float* o = xhat + (size_t)row * D_IN;
  o[tid] = a0; o[tid + 256] = a1; o[tid + 512] = a2;
}

extern "C" void kernel_launch(void* const* d_in, const int* in_sizes, int n_in,
                              void* d_out, int out_size, void* d_ws, size_t ws_size,
                              hipStream_t stream) {
  const float* x    = (const float*)d_in[0];   // [16384][768]
  const float* Wenc = (const float*)d_in[1];   // [12288][768]
  const float* Wdec = (const float*)d_in[2];   // [768][12288]
  float* out_xhat = (float*)d_out;                         // [16384][768]
  float* out_z    = out_xhat + (size_t)N_ROWS * D_IN;      // [16384][12288]

  char* ws = (char*)d_ws;
  unsigned short* xbf  = (unsigned short*)(ws + 0);          // 25,165,824 B
  unsigned short* wbf  = (unsigned short*)(ws + 25165824);   // 18,874,368 B
  float*          WdT  = (float*)        (ws + 44040192);    // 37,748,736 B
  int*            sidx = (int*)          (ws + 81788928);    //  2,097,152 B
  float*          sval = (float*)        (ws + 83886080);    //  2,097,152 B

  // bf16 scores staged inside the z output region (805MB fp32 >= 403MB bf16),
  // consumed by topk_kernel, then overwritten by memset+scatter.
  unsigned short* scores = (unsigned short*)out_z;

  cast_kernel<<<(N_ROWS * D_IN / 4 + 255) / 256, 256, 0, stream>>>(x, xbf, N_ROWS * D_IN / 4);
  cast_kernel<<<(D_LAT * D_IN / 4 + 255) / 256, 256, 0, stream>>>(Wenc, wbf, D_LAT * D_IN / 4);
  transpose_kernel<<<dim3(D_LAT / 32, D_IN / 32), 256, 0, stream>>>(Wdec, WdT);

  gemm_score_kernel<<<dim3(D_LAT / 128, N_ROWS / 128), 256, 0, stream>>>(xbf, wbf, scores);

  topk_kernel<<<N_ROWS, 256, 0, stream>>>(scores, x, Wenc, sidx, sval);

  hipMemsetAsync(out_z, 0, (size_t)N_ROWS * D_LAT * sizeof(float), stream);
  scatter_kernel<<<(N_ROWS * TOPK + 255) / 256, 256, 0, stream>>>(sidx, sval, out_z);

  decode_kernel<<<N_ROWS, 256, 0, stream>>>(sidx, sval, WdT, out_xhat);
}